// Round 11
// baseline (459.830 us; speedup 1.0000x reference)
//
#include <hip/hip_runtime.h>
#include <hip/hip_bf16.h>

#define NNODES 100000
#define NEDGES 1600000
#define ALPHA  0.2f
#define EPSV   1e-9f

// deterministic two-level counting sort geometry
#define NPART  391          // partitions of 256 nodes: p = src >> 8 (max 390)
#define NB1    782          // edge blocks
#define EPB    2048         // edges per block (782*2048 >= NEDGES)

typedef __bf16 bf16x8 __attribute__((ext_vector_type(8)));
typedef float  f32x4  __attribute__((ext_vector_type(4)));
typedef unsigned short u16x8 __attribute__((ext_vector_type(8)));

// manual RNE f32 -> bf16 bits
static __device__ inline unsigned short f2bf(float f) {
    unsigned int u = __float_as_uint(f);
    unsigned int r = u + 0x7fff + ((u >> 16) & 1);
    return (unsigned short)(r >> 16);
}
static __device__ inline float bf2f(unsigned short v) {
    return __uint_as_float((unsigned int)v << 16);
}

// ---------------- init: Wt transpose + per-(block,partition) edge counts -----------
// grid = NB1 blocks. Blocks 0..255 also convert W. Each block LDS-histograms its
// 2048 edges into 391 partition bins (LDS atomics only - no fabric RMWs anywhere).
__global__ __launch_bounds__(256) void k_init(const float* __restrict__ W,
                                              unsigned short* __restrict__ Wt,
                                              const int* __restrict__ src,
                                              int* __restrict__ counts1) {
    __shared__ int hist[NPART];
    const int tid = threadIdx.x;
    const int b = blockIdx.x;
    const int i = b * 256 + tid;
    if (i < 65536) {
        const int n = i >> 8, k = i & 255;
        Wt[i] = f2bf(W[k * 256 + n]);
    }
    for (int t = tid; t < NPART; t += 256) hist[t] = 0;
    __syncthreads();
#pragma unroll
    for (int q = 0; q < 8; ++q) {
        const int e = b * EPB + q * 256 + tid;
        if (e < NEDGES) atomicAdd(&hist[src[e] >> 8], 1);
    }
    __syncthreads();
    for (int t = tid; t < NPART; t += 256) counts1[t * NB1 + b] = hist[t];
}

// ---------------- bf16 MFMA GEMM: Wh = h @ W (verified round-0 form) ----------------
#define BM 128
#define BK 32
#define LSTRIDE 40
__global__ __launch_bounds__(256, 2) void k_gemm(const float* __restrict__ h,
                                                 const unsigned short* __restrict__ Wt,
                                                 unsigned short* __restrict__ Wh) {
    __shared__ __align__(16) unsigned short As[BM * LSTRIDE];
    __shared__ __align__(16) unsigned short Bs[256 * LSTRIDE];
    const int tid  = threadIdx.x;
    const int m0   = blockIdx.x * BM;
    const int wave = tid >> 6;
    const int lane = tid & 63;
    const int wm = (wave & 1) * 64;
    const int wn = (wave >> 1) * 128;
    const int fm = lane & 15;
    const int fq = lane >> 4;
    const int fk = fq * 8;

    f32x4 acc[4][8];
    const f32x4 z = {0.f, 0.f, 0.f, 0.f};
#pragma unroll
    for (int i = 0; i < 4; ++i)
#pragma unroll
        for (int j = 0; j < 8; ++j) acc[i][j] = z;

    const int arow = tid >> 1;
    const int acol = (tid & 1) * 16;
    const bool arow_ok = (m0 + arow) < NNODES;
    const float* hrow = h + (size_t)(m0 + arow) * 256 + acol;

    for (int kc = 0; kc < 256; kc += BK) {
        float4 a0, a1, a2, a3;
        if (arow_ok) {
            a0 = *(const float4*)(hrow + kc + 0);
            a1 = *(const float4*)(hrow + kc + 4);
            a2 = *(const float4*)(hrow + kc + 8);
            a3 = *(const float4*)(hrow + kc + 12);
        } else {
            a0 = a1 = a2 = a3 = make_float4(0.f, 0.f, 0.f, 0.f);
        }
        u16x8 bv[4];
#pragma unroll
        for (int q = 0; q < 4; ++q) {
            const int c = tid + 256 * q;
            const int n = c >> 2, koff = (c & 3) * 8;
            bv[q] = *(const u16x8*)(Wt + n * 256 + kc + koff);
        }
        __syncthreads();
        u16x8 p0, p1;
        p0[0]=f2bf(a0.x); p0[1]=f2bf(a0.y); p0[2]=f2bf(a0.z); p0[3]=f2bf(a0.w);
        p0[4]=f2bf(a1.x); p0[5]=f2bf(a1.y); p0[6]=f2bf(a1.z); p0[7]=f2bf(a1.w);
        p1[0]=f2bf(a2.x); p1[1]=f2bf(a2.y); p1[2]=f2bf(a2.z); p1[3]=f2bf(a2.w);
        p1[4]=f2bf(a3.x); p1[5]=f2bf(a3.y); p1[6]=f2bf(a3.z); p1[7]=f2bf(a3.w);
        *(u16x8*)&As[arow * LSTRIDE + acol]     = p0;
        *(u16x8*)&As[arow * LSTRIDE + acol + 8] = p1;
#pragma unroll
        for (int q = 0; q < 4; ++q) {
            const int c = tid + 256 * q;
            const int n = c >> 2, koff = (c & 3) * 8;
            *(u16x8*)&Bs[n * LSTRIDE + koff] = bv[q];
        }
        __syncthreads();
        bf16x8 af[4], bfr[8];
#pragma unroll
        for (int i = 0; i < 4; ++i)
            af[i] = __builtin_bit_cast(bf16x8,
                *(const u16x8*)&As[(wm + 16 * i + fm) * LSTRIDE + fk]);
#pragma unroll
        for (int j = 0; j < 8; ++j)
            bfr[j] = __builtin_bit_cast(bf16x8,
                *(const u16x8*)&Bs[(wn + 16 * j + fm) * LSTRIDE + fk]);
#pragma unroll
        for (int i = 0; i < 4; ++i)
#pragma unroll
            for (int j = 0; j < 8; ++j)
                acc[i][j] = __builtin_amdgcn_mfma_f32_16x16x32_bf16(af[i], bfr[j], acc[i][j], 0, 0, 0);
    }
#pragma unroll
    for (int i = 0; i < 4; ++i) {
#pragma unroll
        for (int r = 0; r < 4; ++r) {
            const int grow = m0 + wm + 16 * i + fq * 4 + r;
            if (grow < NNODES) {
                unsigned short* orow = Wh + (size_t)grow * 256 + wn + fm;
#pragma unroll
                for (int j = 0; j < 8; ++j)
                    orow[16 * j] = f2bf(acc[i][j][r]);
            }
        }
    }
}

// ---------------- scanP: per-partition exclusive scan over blocks ------------------
// Block p: counts1[p][0..NB1) -> exclusive offsets in place; colTot[p] = total.
__global__ __launch_bounds__(256) void k_scanP(int* __restrict__ counts1,
                                               int* __restrict__ colTot) {
    __shared__ int ssum[256];
    const int p = blockIdx.x;
    const int tid = threadIdx.x;
    int* col = counts1 + (size_t)p * NB1;
    const int base = tid * 4;
    int v[4];
#pragma unroll
    for (int c = 0; c < 4; ++c) v[c] = (base + c < NB1) ? col[base + c] : 0;
    const int s = v[0] + v[1] + v[2] + v[3];
    ssum[tid] = s;
    __syncthreads();
    for (int off = 1; off < 256; off <<= 1) {
        const int t = (tid >= off) ? ssum[tid - off] : 0;
        __syncthreads();
        ssum[tid] += t;
        __syncthreads();
    }
    if (tid == 255) colTot[p] = ssum[255];
    int pr = ssum[tid] - s;
#pragma unroll
    for (int c = 0; c < 4; ++c) {
        if (base + c < NB1) col[base + c] = pr;
        pr += v[c];
    }
}

// ---------------- scanT: exclusive scan of 391 partition totals -> baseP -----------
__global__ __launch_bounds__(256) void k_scanT(const int* __restrict__ colTot,
                                               int* __restrict__ baseP) {
    __shared__ int ssum[256];
    const int tid = threadIdx.x;
    const int i0 = 2 * tid, i1 = 2 * tid + 1;
    const int v0 = (i0 < NPART) ? colTot[i0] : 0;
    const int v1 = (i1 < NPART) ? colTot[i1] : 0;
    const int s = v0 + v1;
    ssum[tid] = s;
    __syncthreads();
    for (int off = 1; off < 256; off <<= 1) {
        const int t = (tid >= off) ? ssum[tid - off] : 0;
        __syncthreads();
        ssum[tid] += t;
        __syncthreads();
    }
    const int ex = ssum[tid] - s;
    if (i0 < NPART) baseP[i0] = ex;
    if (i1 < NPART) baseP[i1] = ex + v0;
    if (tid == 255) baseP[NPART] = NEDGES;
}

// ---------------- scatter_attn: attention + partition-ordered scatter --------------
// Block b re-streams its 2048 edges (same mapping as k_init). Per edge: scalar
// 32-ch label dot -> leakyrelu -> exp; slot = LDS cursor (deterministic base =
// baseP[p] + counts1[p][b], LDS atomicAdd for within-block uniqueness).
// rec[pos] = {dst | (src&255)<<17, w_bits}. Only LDS atomics.
__global__ __launch_bounds__(256) void k_scatter_attn(const float* __restrict__ label,
                                                      const int* __restrict__ src,
                                                      const int* __restrict__ dst,
                                                      const int* __restrict__ counts1,
                                                      const int* __restrict__ baseP,
                                                      uint2* __restrict__ rec) {
    __shared__ int cur[NPART];
    const int tid = threadIdx.x;
    const int b = blockIdx.x;
    for (int t = tid; t < NPART; t += 256)
        cur[t] = baseP[t] + counts1[(size_t)t * NB1 + b];
    __syncthreads();
#pragma unroll
    for (int q = 0; q < 8; ++q) {
        const int e = b * EPB + q * 256 + tid;
        if (e < NEDGES) {
            const int s = src[e], d = dst[e];
            const float4* ls = (const float4*)&label[(size_t)s * 32];
            const float4* ld = (const float4*)&label[(size_t)d * 32];
            float dot = 0.f;
#pragma unroll
            for (int j = 0; j < 8; ++j) {
                const float4 a = ls[j], bb = ld[j];
                dot += a.x * bb.x + a.y * bb.y + a.z * bb.z + a.w * bb.w;
            }
            const float lr = fmaxf(dot, ALPHA * dot);
            const float w = expf(lr);
            const int p = s >> 8;
            const unsigned int loc = (unsigned int)(s & 255);
            const int pos = atomicAdd(&cur[p], 1);
            rec[pos] = make_uint2((unsigned int)d | (loc << 17), __float_as_uint(w));
        }
    }
}

// ---------------- localsort: per-partition 256-bin counting sort -> node CSR -------
// Block p owns rec[baseP[p]..baseP[p+1]). LDS count/scan/scatter by local node,
// writes node-sorted final[] and absolute row_start[node]. Only LDS atomics.
__global__ __launch_bounds__(256) void k_localsort(const uint2* __restrict__ rec,
                                                   const int* __restrict__ baseP,
                                                   uint2* __restrict__ final_,
                                                   int* __restrict__ row_start) {
    __shared__ int cnt[256];
    __shared__ int ssum[256];
    __shared__ int cur[256];
    const int p = blockIdx.x;
    const int tid = threadIdx.x;
    const int lo = baseP[p], hi = baseP[p + 1];
    const int n = hi - lo;
    cnt[tid] = 0;
    __syncthreads();
    for (int i = tid; i < n; i += 256)
        atomicAdd(&cnt[rec[lo + i].x >> 17], 1);
    __syncthreads();
    const int s = cnt[tid];
    ssum[tid] = s;
    __syncthreads();
    for (int off = 1; off < 256; off <<= 1) {
        const int t = (tid >= off) ? ssum[tid - off] : 0;
        __syncthreads();
        ssum[tid] += t;
        __syncthreads();
    }
    const int ex = ssum[tid] - s;
    cur[tid] = ex;
    const int node = p * 256 + tid;
    if (node < NNODES) row_start[node] = lo + ex;
    __syncthreads();
    for (int i = tid; i < n; i += 256) {
        const uint2 r = rec[lo + i];
        const int loc = r.x >> 17;
        const int pos = atomicAdd(&cur[loc], 1);
        final_[lo + pos] = make_uint2(r.x & 0x1FFFFu, r.y);
    }
}

// ---------------- aggregation: 32 lanes/node, 16B gathers, x4 unroll (R0 verified) -
__global__ __launch_bounds__(256) void k_aggregate(const unsigned short* __restrict__ Wh,
                                                   const int* __restrict__ row_start,
                                                   const uint2* __restrict__ sorted_pack,
                                                   float* __restrict__ out) {
    const int node = blockIdx.x * 8 + (threadIdx.x >> 5);
    if (node >= NNODES) return;
    const int sub = threadIdx.x & 31;      // owns channels [sub*8, sub*8+8)
    const int rs = row_start[node];
    const int re = (node == NNODES - 1) ? NEDGES : row_start[node + 1];
    const unsigned short* __restrict__ Whc = Wh + sub * 8;
    float acc[8] = {0.f, 0.f, 0.f, 0.f, 0.f, 0.f, 0.f, 0.f};
    float wsum = 0.f;
    int i = rs;
    for (; i + 4 <= re; i += 4) {
        const uint2 p0 = sorted_pack[i + 0];
        const uint2 p1 = sorted_pack[i + 1];
        const uint2 p2 = sorted_pack[i + 2];
        const uint2 p3 = sorted_pack[i + 3];
        const u16x8 v0 = *(const u16x8*)&Whc[(size_t)p0.x * 256];
        const u16x8 v1 = *(const u16x8*)&Whc[(size_t)p1.x * 256];
        const u16x8 v2 = *(const u16x8*)&Whc[(size_t)p2.x * 256];
        const u16x8 v3 = *(const u16x8*)&Whc[(size_t)p3.x * 256];
        const float w0 = __uint_as_float(p0.y), w1 = __uint_as_float(p1.y);
        const float w2 = __uint_as_float(p2.y), w3 = __uint_as_float(p3.y);
        wsum += (w0 + w1) + (w2 + w3);
#pragma unroll
        for (int c = 0; c < 8; ++c) {
            acc[c] = fmaf(w0, bf2f(v0[c]), acc[c]);
            acc[c] = fmaf(w1, bf2f(v1[c]), acc[c]);
            acc[c] = fmaf(w2, bf2f(v2[c]), acc[c]);
            acc[c] = fmaf(w3, bf2f(v3[c]), acc[c]);
        }
    }
    for (; i < re; ++i) {
        const uint2 p = sorted_pack[i];
        const u16x8 v = *(const u16x8*)&Whc[(size_t)p.x * 256];
        const float w = __uint_as_float(p.y);
        wsum += w;
#pragma unroll
        for (int c = 0; c < 8; ++c) acc[c] = fmaf(w, bf2f(v[c]), acc[c]);
    }
    const float inv = 1.f / fmaxf(wsum, EPSV);
    float4 o0 = make_float4(acc[0] * inv, acc[1] * inv, acc[2] * inv, acc[3] * inv);
    float4 o1 = make_float4(acc[4] * inv, acc[5] * inv, acc[6] * inv, acc[7] * inv);
    float* orow = out + (size_t)node * 256 + sub * 8;
    *(float4*)(orow + 0) = o0;
    *(float4*)(orow + 4) = o1;
}

extern "C" void kernel_launch(void* const* d_in, const int* in_sizes, int n_in,
                              void* d_out, int out_size, void* d_ws, size_t ws_size,
                              hipStream_t stream) {
    const float* h     = (const float*)d_in[0];   // [N,256]
    const float* label = (const float*)d_in[1];   // [N,32]
    const float* W     = (const float*)d_in[2];   // [256,256]
    const int*   adj   = (const int*)d_in[3];     // [2,E]
    const int* src = adj;
    const int* dst = adj + NEDGES;
    float* out = (float*)d_out;

    // workspace layout (bytes). counts1 overlays final's region: counts1 is dead
    // after k_scatter_attn; final is first written in k_localsort. colTot/baseP/
    // row_start live outside the overlay. Max end ~77.4MB (within prior footprint).
    char* ws = (char*)d_ws;
    unsigned short* Wh    = (unsigned short*)(ws + 0);          // 51,200,000
    unsigned short* Wt    = (unsigned short*)(ws + 51200000);   // 131,072
    uint2* rec            = (uint2*)(ws + 51400000);            // E*8 = 12,800,000
    uint2* final_         = (uint2*)(ws + 64200000);            // E*8 = 12,800,000
    int*   counts1        = (int*)  (ws + 64200000);            // 391*782*4 (overlay)
    int*   colTot         = (int*)  (ws + 77000000);            // 391*4
    int*   baseP          = (int*)  (ws + 77002000);            // 392*4
    int*   row_start      = (int*)  (ws + 77010000);            // N*4 = 400,000

    k_init<<<NB1, 256, 0, stream>>>(W, Wt, src, counts1);
    k_gemm<<<(NNODES + BM - 1) / BM, 256, 0, stream>>>(h, Wt, Wh);
    k_scanP<<<NPART, 256, 0, stream>>>(counts1, colTot);
    k_scanT<<<1, 256, 0, stream>>>(colTot, baseP);
    k_scatter_attn<<<NB1, 256, 0, stream>>>(label, src, dst, counts1, baseP, rec);
    k_localsort<<<NPART, 256, 0, stream>>>(rec, baseP, final_, row_start);
    k_aggregate<<<(NNODES + 7) / 8, 256, 0, stream>>>(Wh, row_start, final_, out);
}

// Round 12
// 425.247 us; speedup vs baseline: 1.0813x; 1.0813x over previous
//
#include <hip/hip_runtime.h>
#include <hip/hip_bf16.h>

#define NNODES 100000
#define NEDGES 1600000
#define ALPHA  0.2f
#define EPSV   1e-9f

// deterministic two-level counting sort geometry
#define NPART  391          // partitions of 256 nodes: p = src >> 8 (max 390)
#define NB1    782          // edge blocks
#define EPB    2048         // edges per block (782*2048 >= NEDGES)

typedef __bf16 bf16x8 __attribute__((ext_vector_type(8)));
typedef float  f32x4  __attribute__((ext_vector_type(4)));
typedef unsigned short u16x8 __attribute__((ext_vector_type(8)));

// manual RNE f32 -> bf16 bits
static __device__ inline unsigned short f2bf(float f) {
    unsigned int u = __float_as_uint(f);
    unsigned int r = u + 0x7fff + ((u >> 16) & 1);
    return (unsigned short)(r >> 16);
}
static __device__ inline float bf2f(unsigned short v) {
    return __uint_as_float((unsigned int)v << 16);
}

// ---------------- init: Wt transpose + per-(block,partition) edge counts -----------
__global__ __launch_bounds__(256) void k_init(const float* __restrict__ W,
                                              unsigned short* __restrict__ Wt,
                                              const int* __restrict__ src,
                                              int* __restrict__ counts1) {
    __shared__ int hist[NPART];
    const int tid = threadIdx.x;
    const int b = blockIdx.x;
    const int i = b * 256 + tid;
    if (i < 65536) {
        const int n = i >> 8, k = i & 255;
        Wt[i] = f2bf(W[k * 256 + n]);
    }
    for (int t = tid; t < NPART; t += 256) hist[t] = 0;
    __syncthreads();
#pragma unroll
    for (int q = 0; q < 8; ++q) {
        const int e = b * EPB + q * 256 + tid;
        if (e < NEDGES) atomicAdd(&hist[src[e] >> 8], 1);
    }
    __syncthreads();
    for (int t = tid; t < NPART; t += 256) counts1[t * NB1 + b] = hist[t];
}

// ---------------- bf16 MFMA GEMM: Wh = h @ W (verified round-0 form) ----------------
#define BM 128
#define BK 32
#define LSTRIDE 40
__global__ __launch_bounds__(256, 2) void k_gemm(const float* __restrict__ h,
                                                 const unsigned short* __restrict__ Wt,
                                                 unsigned short* __restrict__ Wh) {
    __shared__ __align__(16) unsigned short As[BM * LSTRIDE];
    __shared__ __align__(16) unsigned short Bs[256 * LSTRIDE];
    const int tid  = threadIdx.x;
    const int m0   = blockIdx.x * BM;
    const int wave = tid >> 6;
    const int lane = tid & 63;
    const int wm = (wave & 1) * 64;
    const int wn = (wave >> 1) * 128;
    const int fm = lane & 15;
    const int fq = lane >> 4;
    const int fk = fq * 8;

    f32x4 acc[4][8];
    const f32x4 z = {0.f, 0.f, 0.f, 0.f};
#pragma unroll
    for (int i = 0; i < 4; ++i)
#pragma unroll
        for (int j = 0; j < 8; ++j) acc[i][j] = z;

    const int arow = tid >> 1;
    const int acol = (tid & 1) * 16;
    const bool arow_ok = (m0 + arow) < NNODES;
    const float* hrow = h + (size_t)(m0 + arow) * 256 + acol;

    for (int kc = 0; kc < 256; kc += BK) {
        float4 a0, a1, a2, a3;
        if (arow_ok) {
            a0 = *(const float4*)(hrow + kc + 0);
            a1 = *(const float4*)(hrow + kc + 4);
            a2 = *(const float4*)(hrow + kc + 8);
            a3 = *(const float4*)(hrow + kc + 12);
        } else {
            a0 = a1 = a2 = a3 = make_float4(0.f, 0.f, 0.f, 0.f);
        }
        u16x8 bv[4];
#pragma unroll
        for (int q = 0; q < 4; ++q) {
            const int c = tid + 256 * q;
            const int n = c >> 2, koff = (c & 3) * 8;
            bv[q] = *(const u16x8*)(Wt + n * 256 + kc + koff);
        }
        __syncthreads();
        u16x8 p0, p1;
        p0[0]=f2bf(a0.x); p0[1]=f2bf(a0.y); p0[2]=f2bf(a0.z); p0[3]=f2bf(a0.w);
        p0[4]=f2bf(a1.x); p0[5]=f2bf(a1.y); p0[6]=f2bf(a1.z); p0[7]=f2bf(a1.w);
        p1[0]=f2bf(a2.x); p1[1]=f2bf(a2.y); p1[2]=f2bf(a2.z); p1[3]=f2bf(a2.w);
        p1[4]=f2bf(a3.x); p1[5]=f2bf(a3.y); p1[6]=f2bf(a3.z); p1[7]=f2bf(a3.w);
        *(u16x8*)&As[arow * LSTRIDE + acol]     = p0;
        *(u16x8*)&As[arow * LSTRIDE + acol + 8] = p1;
#pragma unroll
        for (int q = 0; q < 4; ++q) {
            const int c = tid + 256 * q;
            const int n = c >> 2, koff = (c & 3) * 8;
            *(u16x8*)&Bs[n * LSTRIDE + koff] = bv[q];
        }
        __syncthreads();
        bf16x8 af[4], bfr[8];
#pragma unroll
        for (int i = 0; i < 4; ++i)
            af[i] = __builtin_bit_cast(bf16x8,
                *(const u16x8*)&As[(wm + 16 * i + fm) * LSTRIDE + fk]);
#pragma unroll
        for (int j = 0; j < 8; ++j)
            bfr[j] = __builtin_bit_cast(bf16x8,
                *(const u16x8*)&Bs[(wn + 16 * j + fm) * LSTRIDE + fk]);
#pragma unroll
        for (int i = 0; i < 4; ++i)
#pragma unroll
            for (int j = 0; j < 8; ++j)
                acc[i][j] = __builtin_amdgcn_mfma_f32_16x16x32_bf16(af[i], bfr[j], acc[i][j], 0, 0, 0);
    }
#pragma unroll
    for (int i = 0; i < 4; ++i) {
#pragma unroll
        for (int r = 0; r < 4; ++r) {
            const int grow = m0 + wm + 16 * i + fq * 4 + r;
            if (grow < NNODES) {
                unsigned short* orow = Wh + (size_t)grow * 256 + wn + fm;
#pragma unroll
                for (int j = 0; j < 8; ++j)
                    orow[16 * j] = f2bf(acc[i][j][r]);
            }
        }
    }
}

// ---------------- scanP: per-partition exclusive scan over blocks ------------------
__global__ __launch_bounds__(256) void k_scanP(int* __restrict__ counts1,
                                               int* __restrict__ colTot) {
    __shared__ int ssum[256];
    const int p = blockIdx.x;
    const int tid = threadIdx.x;
    int* col = counts1 + (size_t)p * NB1;
    const int base = tid * 4;
    int v[4];
#pragma unroll
    for (int c = 0; c < 4; ++c) v[c] = (base + c < NB1) ? col[base + c] : 0;
    const int s = v[0] + v[1] + v[2] + v[3];
    ssum[tid] = s;
    __syncthreads();
    for (int off = 1; off < 256; off <<= 1) {
        const int t = (tid >= off) ? ssum[tid - off] : 0;
        __syncthreads();
        ssum[tid] += t;
        __syncthreads();
    }
    if (tid == 255) colTot[p] = ssum[255];
    int pr = ssum[tid] - s;
#pragma unroll
    for (int c = 0; c < 4; ++c) {
        if (base + c < NB1) col[base + c] = pr;
        pr += v[c];
    }
}

// ---------------- scanT: exclusive scan of 391 partition totals -> baseP -----------
__global__ __launch_bounds__(256) void k_scanT(const int* __restrict__ colTot,
                                               int* __restrict__ baseP) {
    __shared__ int ssum[256];
    const int tid = threadIdx.x;
    const int i0 = 2 * tid, i1 = 2 * tid + 1;
    const int v0 = (i0 < NPART) ? colTot[i0] : 0;
    const int v1 = (i1 < NPART) ? colTot[i1] : 0;
    const int s = v0 + v1;
    ssum[tid] = s;
    __syncthreads();
    for (int off = 1; off < 256; off <<= 1) {
        const int t = (tid >= off) ? ssum[tid - off] : 0;
        __syncthreads();
        ssum[tid] += t;
        __syncthreads();
    }
    const int ex = ssum[tid] - s;
    if (i0 < NPART) baseP[i0] = ex;
    if (i1 < NPART) baseP[i1] = ex + v0;
    if (tid == 255) baseP[NPART] = NEDGES;
}

// ---------------- scatter_attn: attention + partition-ordered scatter --------------
// R0-verified 4-lane quad attn structure (the R11 version spilled: 16 float4/edge
// x8 unroll -> ~512 live VGPRs). 64 quads/block, 32 non-unrolled iterations cover
// the block's 2048 edges. Quad: coalesced 32B/lane label loads, shfl_xor reduce;
// lane0: exp + LDS partition-cursor atomicAdd + 8B rec write. No fabric RMWs.
__global__ __launch_bounds__(256) void k_scatter_attn(const float* __restrict__ label,
                                                      const int* __restrict__ src,
                                                      const int* __restrict__ dst,
                                                      const int* __restrict__ counts1,
                                                      const int* __restrict__ baseP,
                                                      uint2* __restrict__ rec) {
    __shared__ int cur[NPART];
    const int tid = threadIdx.x;
    const int b = blockIdx.x;
    for (int t = tid; t < NPART; t += 256)
        cur[t] = baseP[t] + counts1[(size_t)t * NB1 + b];
    __syncthreads();
    const int qid = tid >> 2;        // quad id 0..63
    const int l4  = tid & 3;         // lane within quad
#pragma unroll 1
    for (int it = 0; it < 32; ++it) {
        const int e = b * EPB + it * 64 + qid;
        if (e >= NEDGES) continue;
        const int s = src[e], d = dst[e];
        const float4* ls = (const float4*)&label[(size_t)s * 32 + l4 * 8];
        const float4* ld = (const float4*)&label[(size_t)d * 32 + l4 * 8];
        const float4 a0 = ls[0], a1 = ls[1];
        const float4 b0 = ld[0], b1 = ld[1];
        float dot = a0.x * b0.x + a0.y * b0.y + a0.z * b0.z + a0.w * b0.w
                  + a1.x * b1.x + a1.y * b1.y + a1.z * b1.z + a1.w * b1.w;
        dot += __shfl_xor(dot, 1);
        dot += __shfl_xor(dot, 2);
        if (l4 == 0) {
            const float lr = dot >= 0.f ? dot : ALPHA * dot;
            const float w = expf(lr);
            const int p = s >> 8;
            const unsigned int loc = (unsigned int)(s & 255);
            const int pos = atomicAdd(&cur[p], 1);
            rec[pos] = make_uint2((unsigned int)d | (loc << 17), __float_as_uint(w));
        }
    }
}

// ---------------- localsort: per-partition 256-bin counting sort -> node CSR -------
__global__ __launch_bounds__(256) void k_localsort(const uint2* __restrict__ rec,
                                                   const int* __restrict__ baseP,
                                                   uint2* __restrict__ final_,
                                                   int* __restrict__ row_start) {
    __shared__ int cnt[256];
    __shared__ int ssum[256];
    __shared__ int cur[256];
    const int p = blockIdx.x;
    const int tid = threadIdx.x;
    const int lo = baseP[p], hi = baseP[p + 1];
    const int n = hi - lo;
    cnt[tid] = 0;
    __syncthreads();
    for (int i = tid; i < n; i += 256)
        atomicAdd(&cnt[rec[lo + i].x >> 17], 1);
    __syncthreads();
    const int s = cnt[tid];
    ssum[tid] = s;
    __syncthreads();
    for (int off = 1; off < 256; off <<= 1) {
        const int t = (tid >= off) ? ssum[tid - off] : 0;
        __syncthreads();
        ssum[tid] += t;
        __syncthreads();
    }
    const int ex = ssum[tid] - s;
    cur[tid] = ex;
    const int node = p * 256 + tid;
    if (node < NNODES) row_start[node] = lo + ex;
    __syncthreads();
    for (int i = tid; i < n; i += 256) {
        const uint2 r = rec[lo + i];
        const int loc = r.x >> 17;
        const int pos = atomicAdd(&cur[loc], 1);
        final_[lo + pos] = make_uint2(r.x & 0x1FFFFu, r.y);
    }
}

// ---------------- aggregation: 32 lanes/node, 16B gathers, x4 unroll (R0 verified) -
__global__ __launch_bounds__(256) void k_aggregate(const unsigned short* __restrict__ Wh,
                                                   const int* __restrict__ row_start,
                                                   const uint2* __restrict__ sorted_pack,
                                                   float* __restrict__ out) {
    const int node = blockIdx.x * 8 + (threadIdx.x >> 5);
    if (node >= NNODES) return;
    const int sub = threadIdx.x & 31;      // owns channels [sub*8, sub*8+8)
    const int rs = row_start[node];
    const int re = (node == NNODES - 1) ? NEDGES : row_start[node + 1];
    const unsigned short* __restrict__ Whc = Wh + sub * 8;
    float acc[8] = {0.f, 0.f, 0.f, 0.f, 0.f, 0.f, 0.f, 0.f};
    float wsum = 0.f;
    int i = rs;
    for (; i + 4 <= re; i += 4) {
        const uint2 p0 = sorted_pack[i + 0];
        const uint2 p1 = sorted_pack[i + 1];
        const uint2 p2 = sorted_pack[i + 2];
        const uint2 p3 = sorted_pack[i + 3];
        const u16x8 v0 = *(const u16x8*)&Whc[(size_t)p0.x * 256];
        const u16x8 v1 = *(const u16x8*)&Whc[(size_t)p1.x * 256];
        const u16x8 v2 = *(const u16x8*)&Whc[(size_t)p2.x * 256];
        const u16x8 v3 = *(const u16x8*)&Whc[(size_t)p3.x * 256];
        const float w0 = __uint_as_float(p0.y), w1 = __uint_as_float(p1.y);
        const float w2 = __uint_as_float(p2.y), w3 = __uint_as_float(p3.y);
        wsum += (w0 + w1) + (w2 + w3);
#pragma unroll
        for (int c = 0; c < 8; ++c) {
            acc[c] = fmaf(w0, bf2f(v0[c]), acc[c]);
            acc[c] = fmaf(w1, bf2f(v1[c]), acc[c]);
            acc[c] = fmaf(w2, bf2f(v2[c]), acc[c]);
            acc[c] = fmaf(w3, bf2f(v3[c]), acc[c]);
        }
    }
    for (; i < re; ++i) {
        const uint2 p = sorted_pack[i];
        const u16x8 v = *(const u16x8*)&Whc[(size_t)p.x * 256];
        const float w = __uint_as_float(p.y);
        wsum += w;
#pragma unroll
        for (int c = 0; c < 8; ++c) acc[c] = fmaf(w, bf2f(v[c]), acc[c]);
    }
    const float inv = 1.f / fmaxf(wsum, EPSV);
    float4 o0 = make_float4(acc[0] * inv, acc[1] * inv, acc[2] * inv, acc[3] * inv);
    float4 o1 = make_float4(acc[4] * inv, acc[5] * inv, acc[6] * inv, acc[7] * inv);
    float* orow = out + (size_t)node * 256 + sub * 8;
    *(float4*)(orow + 0) = o0;
    *(float4*)(orow + 4) = o1;
}

extern "C" void kernel_launch(void* const* d_in, const int* in_sizes, int n_in,
                              void* d_out, int out_size, void* d_ws, size_t ws_size,
                              hipStream_t stream) {
    const float* h     = (const float*)d_in[0];   // [N,256]
    const float* label = (const float*)d_in[1];   // [N,32]
    const float* W     = (const float*)d_in[2];   // [256,256]
    const int*   adj   = (const int*)d_in[3];     // [2,E]
    const int* src = adj;
    const int* dst = adj + NEDGES;
    float* out = (float*)d_out;

    // workspace layout (bytes). counts1 overlays final's region: counts1 is dead
    // after k_scatter_attn; final_ is first written in k_localsort.
    char* ws = (char*)d_ws;
    unsigned short* Wh    = (unsigned short*)(ws + 0);          // 51,200,000
    unsigned short* Wt    = (unsigned short*)(ws + 51200000);   // 131,072
    uint2* rec            = (uint2*)(ws + 51400000);            // E*8 = 12,800,000
    uint2* final_         = (uint2*)(ws + 64200000);            // E*8 = 12,800,000
    int*   counts1        = (int*)  (ws + 64200000);            // 391*782*4 (overlay)
    int*   colTot         = (int*)  (ws + 77000000);            // 391*4
    int*   baseP          = (int*)  (ws + 77002000);            // 392*4
    int*   row_start      = (int*)  (ws + 77010000);            // N*4 = 400,000

    k_init<<<NB1, 256, 0, stream>>>(W, Wt, src, counts1);
    k_gemm<<<(NNODES + BM - 1) / BM, 256, 0, stream>>>(h, Wt, Wh);
    k_scanP<<<NPART, 256, 0, stream>>>(counts1, colTot);
    k_scanT<<<1, 256, 0, stream>>>(colTot, baseP);
    k_scatter_attn<<<NB1, 256, 0, stream>>>(label, src, dst, counts1, baseP, rec);
    k_localsort<<<NPART, 256, 0, stream>>>(rec, baseP, final_, row_start);
    k_aggregate<<<(NNODES + 7) / 8, 256, 0, stream>>>(Wh, row_start, final_, out);
}